// Round 7
// baseline (59.836 us; speedup 1.0000x reference)
//
#include <hip/hip_runtime.h>
#include <hip/hip_bf16.h>

constexpr int S  = 256;
constexpr int D  = 768;
constexpr int KQ = 16;         // K slices
constexpr int KS = D / KQ;     // 48
constexpr int NT = KS / 16;    // 3 k-tiles of 16
constexpr int GROWS = KQ * S;  // G row stride in floats (slices interleaved per row)

// Stage 1: per-batch Gram slices, fp32. G layout is ROW-INTERLEAVED:
//   G[((batch*256 + row)*16 + kq)*256 + col]
// so that stage 2 reads a row's 16 slices as ONE contiguous 16 KB block
// (round-6 post-mortem: 2 MB-stride slice-major reads ran at 480 GB/s).
// Grid (4, 8, 16): x = 64-col strip, y = batch, z = kq. 512 blocks (2/CU).
// Micro-tile 16x4: per kk, 4 broadcast ds_read_b128 (A) + 1 conflict-free (B)
// feed 64 FMAs. Numerics bit-identical to the validated round-6 kernel.
__global__ __launch_bounds__(256) void gram_kernel(const float* __restrict__ X,
                                                   float* __restrict__ G,
                                                   float* __restrict__ logits,
                                                   unsigned* __restrict__ cnt) {
    const int strip = blockIdx.x;
    const int batch = blockIdx.y;
    const int kq    = blockIdx.z;
    const int t     = threadIdx.x;

    if (strip == 0 && kq == 0) {       // stream-ordered zeroing for stage 2
        if (t < 4) logits[batch * 4 + t] = 0.0f;
        else if (t == 4) cnt[batch] = 0u;
    }

    const int tJ    = strip * 64;
    const int kbase = kq * KS;
    const float* Xb = X + (size_t)batch * S * D;
    float* Gb = G + ((size_t)batch * S * KQ + kq) * S;   // row r at Gb + r*GROWS

    __shared__ float As[16][260];   // [k][row 0..255]
    __shared__ float Bs[16][68];    // [k][col 0..63]

    const int ty = t >> 4;          // 0..15 -> rows ty*16..+15
    const int tx = t & 15;          // 0..15 -> cols tx*4..+3

    const int srow = t >> 2;
    const int skq  = (t & 3) * 4;
    const float* pA = Xb + (size_t)t * D + kbase;
    const float* pB = Xb + (size_t)(tJ + srow) * D + kbase + skq;

    float4 ra0 = *(const float4*)(pA + 0);
    float4 ra1 = *(const float4*)(pA + 4);
    float4 ra2 = *(const float4*)(pA + 8);
    float4 ra3 = *(const float4*)(pA + 12);
    float4 rb  = *(const float4*)(pB);

    float4 acc_[16];
#pragma unroll
    for (int r = 0; r < 16; ++r) acc_[r] = make_float4(0.f, 0.f, 0.f, 0.f);

    for (int kt = 0; kt < NT; ++kt) {
        __syncthreads();            // previous compute's LDS reads drained
        As[0][t]  = ra0.x; As[1][t]  = ra0.y; As[2][t]  = ra0.z; As[3][t]  = ra0.w;
        As[4][t]  = ra1.x; As[5][t]  = ra1.y; As[6][t]  = ra1.z; As[7][t]  = ra1.w;
        As[8][t]  = ra2.x; As[9][t]  = ra2.y; As[10][t] = ra2.z; As[11][t] = ra2.w;
        As[12][t] = ra3.x; As[13][t] = ra3.y; As[14][t] = ra3.z; As[15][t] = ra3.w;
        Bs[skq + 0][srow] = rb.x; Bs[skq + 1][srow] = rb.y;
        Bs[skq + 2][srow] = rb.z; Bs[skq + 3][srow] = rb.w;
        if (kt + 1 < NT) {          // prefetch next k-tile; hides under FMA burst
            const int ko = (kt + 1) * 16;
            ra0 = *(const float4*)(pA + ko + 0);
            ra1 = *(const float4*)(pA + ko + 4);
            ra2 = *(const float4*)(pA + ko + 8);
            ra3 = *(const float4*)(pA + ko + 12);
            rb  = *(const float4*)(pB + ko);
        }
        __syncthreads();
#pragma unroll
        for (int kk = 0; kk < 16; ++kk) {
            const float4 f0 = *(const float4*)&As[kk][ty * 16 + 0];
            const float4 f1 = *(const float4*)&As[kk][ty * 16 + 4];
            const float4 f2 = *(const float4*)&As[kk][ty * 16 + 8];
            const float4 f3 = *(const float4*)&As[kk][ty * 16 + 12];
            const float4 bv = *(const float4*)&Bs[kk][tx * 4];
#define FMA1(R, AV) \
            acc_[R].x = fmaf((AV), bv.x, acc_[R].x); \
            acc_[R].y = fmaf((AV), bv.y, acc_[R].y); \
            acc_[R].z = fmaf((AV), bv.z, acc_[R].z); \
            acc_[R].w = fmaf((AV), bv.w, acc_[R].w);
            FMA1(0,  f0.x) FMA1(1,  f0.y) FMA1(2,  f0.z) FMA1(3,  f0.w)
            FMA1(4,  f1.x) FMA1(5,  f1.y) FMA1(6,  f1.z) FMA1(7,  f1.w)
            FMA1(8,  f2.x) FMA1(9,  f2.y) FMA1(10, f2.z) FMA1(11, f2.w)
            FMA1(12, f3.x) FMA1(13, f3.y) FMA1(14, f3.z) FMA1(15, f3.w)
#undef FMA1
        }
    }

    // Coalesced store: row ty*16+r (stride GROWS), cols tJ+tx*4..+3.
    float* gout = Gb + (size_t)(ty * 16) * GROWS + tJ + tx * 4;
#pragma unroll
    for (int r = 0; r < 16; ++r)
        *(float4*)(gout + (size_t)r * GROWS) = acc_[r];
}

// Stage 2 (fully fused): wave handles position b = blockIdx.x*4 + wave.
// Visibility read is one contiguous <=16 KB row block; triangle guard masks
// lanes with c0 > b (their gs stays 0; VTEST guards c < b anyway).
// Numerics identical to validated round 6 (same sum tree, same formula).
__global__ __launch_bounds__(256) void vishead_kernel(const float* __restrict__ X,
                                                      const float* __restrict__ Wm,
                                                      const float* __restrict__ G,
                                                      float* __restrict__ logits,
                                                      unsigned* __restrict__ cnt,
                                                      float* __restrict__ out) {
    const int batch = blockIdx.y;
    const int wave  = threadIdx.x >> 6;
    const int lane  = threadIdx.x & 63;
    const int b     = blockIdx.x * 4 + wave;

    // ---- visibility of b from 0: 16 slice segments, contiguous per row ----
    const float* rbp = G + (size_t)(batch * S + b) * GROWS + 4 * lane;
    float4 s0 = make_float4(0.f, 0.f, 0.f, 0.f), s1 = s0, s2 = s0, s3 = s0;
    if (4 * lane <= b) {            // triangle: lanes past b contribute nothing
#pragma unroll
        for (int sl = 0; sl < 4; ++sl) {
            const float4 v0 = *(const float4*)(rbp + (size_t)(4 * sl + 0) * S);
            const float4 v1 = *(const float4*)(rbp + (size_t)(4 * sl + 1) * S);
            const float4 v2 = *(const float4*)(rbp + (size_t)(4 * sl + 2) * S);
            const float4 v3 = *(const float4*)(rbp + (size_t)(4 * sl + 3) * S);
            s0.x += v0.x; s0.y += v0.y; s0.z += v0.z; s0.w += v0.w;
            s1.x += v1.x; s1.y += v1.y; s1.z += v1.z; s1.w += v1.w;
            s2.x += v2.x; s2.y += v2.y; s2.z += v2.z; s2.w += v2.w;
            s3.x += v3.x; s3.y += v3.y; s3.z += v3.z; s3.w += v3.w;
        }
    }
    float4 gs;
    gs.x = (s0.x + s1.x) + (s2.x + s3.x);
    gs.y = (s0.y + s1.y) + (s2.y + s3.y);
    gs.z = (s0.z + s1.z) + (s2.z + s3.z);
    gs.w = (s0.w + s1.w) + (s2.w + s3.w);

    const int bq = b & 3;                       // wave-uniform component select
    float sel = (bq == 0) ? gs.x : ((bq == 1) ? gs.y : ((bq == 2) ? gs.z : gs.w));
    const float gb = __shfl(sel, b >> 2);
    const float g0 = __shfl(gs.x, 0);
    const float denom = (b > 0) ? (float)b : 1.0f;

    bool blocked = false;
    {
        const int c0 = 4 * lane;
#define VTEST(Q, GV) { const int c = c0 + (Q); \
        const float line = gb + ((g0 - gb) * (float)(b - c)) / denom; \
        if (c >= 1 && c < b && (GV) >= line) blocked = true; }
        VTEST(0, gs.x) VTEST(1, gs.y) VTEST(2, gs.z) VTEST(3, gs.w)
#undef VTEST
    }
    const bool visflag = (b >= 1) && !__any(blocked);

    // ---- P[b][:] = x_b @ W ----
    const float* xs = X + ((size_t)batch * S + b) * D;
    float a0 = 0.f, a1 = 0.f, a2 = 0.f, a3 = 0.f;
#pragma unroll
    for (int i = 0; i < 3; ++i) {
        const int d0 = (lane + 64 * i) * 4;
        const float4 xv = *(const float4*)(xs + d0);
        const float xf[4] = {xv.x, xv.y, xv.z, xv.w};
#pragma unroll
        for (int j = 0; j < 4; ++j) {
            const float4 wq = *(const float4*)(Wm + (size_t)(d0 + j) * 4);
            a0 = fmaf(xf[j], wq.x, a0);
            a1 = fmaf(xf[j], wq.y, a1);
            a2 = fmaf(xf[j], wq.z, a2);
            a3 = fmaf(xf[j], wq.w, a3);
        }
    }
#pragma unroll
    for (int off = 32; off; off >>= 1) {
        a0 += __shfl_xor(a0, off);
        a1 += __shfl_xor(a1, off);
        a2 += __shfl_xor(a2, off);
        a3 += __shfl_xor(a3, off);
    }
    if (lane == 0 && visflag) {
        atomicAdd(&logits[batch * 4 + 0], a0);
        atomicAdd(&logits[batch * 4 + 1], a1);
        atomicAdd(&logits[batch * 4 + 2], a2);
        atomicAdd(&logits[batch * 4 + 3], a3);
    }

    __syncthreads();                 // all 4 waves' atomics issued & drained
    if (threadIdx.x == 0) {
        __threadfence();
        const unsigned old = atomicAdd(&cnt[batch], 1u);
        if (old == 63u) {            // last block for this batch: finalize
            const float l0 = atomicAdd(&logits[batch * 4 + 0], 0.0f);
            const float l1 = atomicAdd(&logits[batch * 4 + 1], 0.0f);
            const float l2 = atomicAdd(&logits[batch * 4 + 2], 0.0f);
            const float l3 = atomicAdd(&logits[batch * 4 + 3], 0.0f);
            const float m = fmaxf(fmaxf(l0, l1), fmaxf(l2, l3));
            const float lse = logf(expf(l0 - m) + expf(l1 - m) +
                                   expf(l2 - m) + expf(l3 - m));
            out[batch * 4 + 0] = l0 - m - lse;
            out[batch * 4 + 1] = l1 - m - lse;
            out[batch * 4 + 2] = l2 - m - lse;
            out[batch * 4 + 3] = l3 - m - lse;
        }
    }
}

extern "C" void kernel_launch(void* const* d_in, const int* in_sizes, int n_in,
                              void* d_out, int out_size, void* d_ws, size_t ws_size,
                              hipStream_t stream) {
    const float* X  = (const float*)d_in[0];   // [8, 256, 768] fp32
    const float* Wm = (const float*)d_in[1];   // [768, 4] fp32
    float* out = (float*)d_out;                // [8, 4] fp32

    float* ws = (float*)d_ws;
    float*    logits = ws;                     // 32 floats
    unsigned* cnt    = (unsigned*)(ws + 32);   // 8 uints
    float*    G      = ws + 64;                // 8 x 256 x 16 x 256 fp32 (~33.5 MB)

    gram_kernel   <<<dim3(4, 8, 16), 256, 0, stream>>>(X, G, logits, cnt);
    vishead_kernel<<<dim3(64, 8),    256, 0, stream>>>(X, Wm, G, logits, cnt, out);
}

// Round 8
// 27.796 us; speedup vs baseline: 2.1527x; 2.1527x over previous
//
#include <hip/hip_runtime.h>
#include <hip/hip_bf16.h>

constexpr int S  = 256;
constexpr int D  = 768;
constexpr int KQ = 8;          // K slices
constexpr int KS = D / KQ;     // 96
constexpr int GROWS = KQ * S;  // 2048 floats: G[((batch*256+row)*8+kq)*256+col]

typedef _Float16 half8  __attribute__((ext_vector_type(8)));
typedef _Float16 half4v __attribute__((ext_vector_type(4)));
typedef float    f32x4  __attribute__((ext_vector_type(4)));

// Split X into fp16 hi/lo: x = hi + lo + O(2^-22 x). 1536 blocks x 256 thr.
__global__ __launch_bounds__(256) void convert_kernel(const float* __restrict__ X,
                                                      _Float16* __restrict__ Xh,
                                                      _Float16* __restrict__ Xl) {
    const int i = (blockIdx.x * 256 + threadIdx.x) * 4;
    const float4 v = *(const float4*)(X + i);
    half4v h, l;
    h.x = (_Float16)v.x; l.x = (_Float16)(v.x - (float)h.x);
    h.y = (_Float16)v.y; l.y = (_Float16)(v.y - (float)h.y);
    h.z = (_Float16)v.z; l.z = (_Float16)(v.z - (float)h.z);
    h.w = (_Float16)v.w; l.w = (_Float16)(v.w - (float)h.w);
    *(half4v*)(Xh + i) = h;
    *(half4v*)(Xl + i) = l;
}

// Gram via MFMA: G_slice = Ah*Bh^T + Ah*Bl^T + Al*Bh^T (fp32 accumulate).
// Grid (16, 8, 8): x = 64x64 tile (ti*4+tj), y = batch, z = kq. 1024 blocks.
// K=96 staged once in LDS (53 KB, ~3 blocks/CU); wave w owns rows 16w..+15,
// N_rep=4 -> 36 MFMA + 30 ds_read_b128 per wave total. fp16-split error
// ~7e-6 absolute, same order as validated slice-reorder perturbations.
__global__ __launch_bounds__(256) void gram_kernel(const _Float16* __restrict__ Xh,
                                                   const _Float16* __restrict__ Xl,
                                                   float* __restrict__ G) {
    const int ti    = blockIdx.x >> 2;
    const int tj    = blockIdx.x & 3;
    const int batch = blockIdx.y;
    const int kq    = blockIdx.z;

    const size_t xoff = (size_t)batch * S * D + kq * KS;
    const _Float16* Xhq = Xh + xoff;
    const _Float16* Xlq = Xl + xoff;

    // stride 104 halfs = 208B: 16B-aligned, rows land on ~2-way bank pattern
    __shared__ _Float16 Ah[64][104], Al[64][104], Bh[64][104], Bl[64][104];

    const int t    = threadIdx.x;
    const int srow = t >> 2;          // 0..63
    const int sk   = (t & 3) * 24;    // 0,24,48,72 (3 x 8-half chunks each)

#pragma unroll
    for (int c = 0; c < 3; ++c) {
        const int ko = sk + c * 8;    // 16B-aligned half offset
        *(int4*)&Ah[srow][ko] = *(const int4*)(Xhq + (size_t)(ti * 64 + srow) * D + ko);
        *(int4*)&Al[srow][ko] = *(const int4*)(Xlq + (size_t)(ti * 64 + srow) * D + ko);
        *(int4*)&Bh[srow][ko] = *(const int4*)(Xhq + (size_t)(tj * 64 + srow) * D + ko);
        *(int4*)&Bl[srow][ko] = *(const int4*)(Xlq + (size_t)(tj * 64 + srow) * D + ko);
    }
    __syncthreads();

    const int lane = t & 63;
    const int w    = t >> 6;          // wave -> rows 16w..16w+15
    const int frow = lane & 15;       // fragment row/col within 16
    const int fko  = (lane >> 4) * 8; // fragment k offset (8 halfs)

    f32x4 acc[4] = {};
#pragma unroll
    for (int ks = 0; ks < 3; ++ks) {
        const int k0 = ks * 32 + fko;
        const half8 ah = *(const half8*)&Ah[w * 16 + frow][k0];
        const half8 al = *(const half8*)&Al[w * 16 + frow][k0];
#pragma unroll
        for (int n = 0; n < 4; ++n) {
            const half8 bh = *(const half8*)&Bh[n * 16 + frow][k0];
            const half8 bl = *(const half8*)&Bl[n * 16 + frow][k0];
            acc[n] = __builtin_amdgcn_mfma_f32_16x16x32_f16(ah, bh, acc[n], 0, 0, 0);
            acc[n] = __builtin_amdgcn_mfma_f32_16x16x32_f16(ah, bl, acc[n], 0, 0, 0);
            acc[n] = __builtin_amdgcn_mfma_f32_16x16x32_f16(al, bh, acc[n], 0, 0, 0);
        }
    }

    // C/D layout (m89-verified): col = lane&15, row = (lane>>4)*4 + reg.
    float* gout = G + ((size_t)(batch * S + ti * 64 + w * 16 + (lane >> 4) * 4) * KQ + kq) * S
                    + tj * 64 + frow;
#pragma unroll
    for (int n = 0; n < 4; ++n)
#pragma unroll
        for (int r = 0; r < 4; ++r)
            gout[(size_t)r * GROWS + n * 16] = acc[n][r];
}

// Stage 2: wave handles position b = blockIdx.x*4 + wave.
//   vis: contiguous 8-slice row read (8 KB) + triangle guard; P = x_b @ W.
// No atomics (round-7 post-mortem: same-address atomicAdd chain cost ~30us).
__global__ __launch_bounds__(256) void visxw_kernel(const float* __restrict__ X,
                                                    const float* __restrict__ Wm,
                                                    const float* __restrict__ G,
                                                    float* __restrict__ P,
                                                    float* __restrict__ wv) {
    const int batch = blockIdx.y;
    const int wave  = threadIdx.x >> 6;
    const int lane  = threadIdx.x & 63;
    const int b     = blockIdx.x * 4 + wave;

    // ---- visibility of b from 0: sum 8 slice segments of row b ----
    const float* rbp = G + (size_t)(batch * S + b) * GROWS + 4 * lane;
    float4 s0 = make_float4(0.f, 0.f, 0.f, 0.f), s1 = s0, s2 = s0, s3 = s0;
    if (4 * lane <= b) {            // triangle: lanes past b contribute nothing
#pragma unroll
        for (int sl = 0; sl < 2; ++sl) {
            const float4 v0 = *(const float4*)(rbp + (size_t)(4 * sl + 0) * S);
            const float4 v1 = *(const float4*)(rbp + (size_t)(4 * sl + 1) * S);
            const float4 v2 = *(const float4*)(rbp + (size_t)(4 * sl + 2) * S);
            const float4 v3 = *(const float4*)(rbp + (size_t)(4 * sl + 3) * S);
            s0.x += v0.x; s0.y += v0.y; s0.z += v0.z; s0.w += v0.w;
            s1.x += v1.x; s1.y += v1.y; s1.z += v1.z; s1.w += v1.w;
            s2.x += v2.x; s2.y += v2.y; s2.z += v2.z; s2.w += v2.w;
            s3.x += v3.x; s3.y += v3.y; s3.z += v3.z; s3.w += v3.w;
        }
    }
    float4 gs;
    gs.x = (s0.x + s1.x) + (s2.x + s3.x);
    gs.y = (s0.y + s1.y) + (s2.y + s3.y);
    gs.z = (s0.z + s1.z) + (s2.z + s3.z);
    gs.w = (s0.w + s1.w) + (s2.w + s3.w);

    const int bq = b & 3;                       // wave-uniform component select
    float sel = (bq == 0) ? gs.x : ((bq == 1) ? gs.y : ((bq == 2) ? gs.z : gs.w));
    const float gb = __shfl(sel, b >> 2);
    const float g0 = __shfl(gs.x, 0);
    const float denom = (b > 0) ? (float)b : 1.0f;

    bool blocked = false;
    {
        const int c0 = 4 * lane;
#define VTEST(Q, GV) { const int c = c0 + (Q); \
        const float line = gb + ((g0 - gb) * (float)(b - c)) / denom; \
        if (c >= 1 && c < b && (GV) >= line) blocked = true; }
        VTEST(0, gs.x) VTEST(1, gs.y) VTEST(2, gs.z) VTEST(3, gs.w)
#undef VTEST
    }
    const bool visflag = (b >= 1) && !__any(blocked);

    // ---- P[b][:] = x_b @ W ----
    const float* xs = X + ((size_t)batch * S + b) * D;
    float a0 = 0.f, a1 = 0.f, a2 = 0.f, a3 = 0.f;
#pragma unroll
    for (int i = 0; i < 3; ++i) {
        const int d0 = (lane + 64 * i) * 4;
        const float4 xv = *(const float4*)(xs + d0);
        const float xf[4] = {xv.x, xv.y, xv.z, xv.w};
#pragma unroll
        for (int j = 0; j < 4; ++j) {
            const float4 wq = *(const float4*)(Wm + (size_t)(d0 + j) * 4);
            a0 = fmaf(xf[j], wq.x, a0);
            a1 = fmaf(xf[j], wq.y, a1);
            a2 = fmaf(xf[j], wq.z, a2);
            a3 = fmaf(xf[j], wq.w, a3);
        }
    }
#pragma unroll
    for (int off = 32; off; off >>= 1) {
        a0 += __shfl_xor(a0, off);
        a1 += __shfl_xor(a1, off);
        a2 += __shfl_xor(a2, off);
        a3 += __shfl_xor(a3, off);
    }
    if (lane == 0) {
        float4 o = {a0, a1, a2, a3};
        *(float4*)(P + ((size_t)batch * S + b) * 4) = o;
        wv[batch * S + b] = visflag ? 1.0f : 0.0f;
    }
}

// logits_k = sum_s w_s * P[s][k]; log_softmax. Grid 8 blocks, wave k per logit.
__global__ __launch_bounds__(256) void head_kernel(const float* __restrict__ P,
                                                   const float* __restrict__ wv,
                                                   float* __restrict__ out) {
    const int batch = blockIdx.x;
    const int k     = threadIdx.x >> 6;
    const int lane  = threadIdx.x & 63;

    float sum = 0.f;
#pragma unroll
    for (int i = 0; i < 4; ++i) {
        const int s = lane + 64 * i;
        sum = fmaf(wv[batch * S + s], P[((size_t)batch * S + s) * 4 + k], sum);
    }
#pragma unroll
    for (int off = 32; off; off >>= 1) sum += __shfl_xor(sum, off);

    __shared__ float lsh[4];
    if (lane == 0) lsh[k] = sum;
    __syncthreads();

    if (threadIdx.x == 0) {
        const float l0 = lsh[0], l1 = lsh[1], l2 = lsh[2], l3 = lsh[3];
        const float m = fmaxf(fmaxf(l0, l1), fmaxf(l2, l3));
        const float lse = logf(expf(l0 - m) + expf(l1 - m) + expf(l2 - m) + expf(l3 - m));
        out[batch * 4 + 0] = l0 - m - lse;
        out[batch * 4 + 1] = l1 - m - lse;
        out[batch * 4 + 2] = l2 - m - lse;
        out[batch * 4 + 3] = l3 - m - lse;
    }
}

extern "C" void kernel_launch(void* const* d_in, const int* in_sizes, int n_in,
                              void* d_out, int out_size, void* d_ws, size_t ws_size,
                              hipStream_t stream) {
    const float* X  = (const float*)d_in[0];   // [8, 256, 768] fp32
    const float* Wm = (const float*)d_in[1];   // [768, 4] fp32
    float* out = (float*)d_out;                // [8, 4] fp32

    float* ws = (float*)d_ws;
    float* P  = ws;                                  // 8192 floats
    float* wv = ws + 8192;                           // 2048 floats
    float* G  = ws + 10240;                          // 8*256*8*256 = 4.19M floats
    _Float16* Xh = (_Float16*)(ws + 10240 + 4194304);
    _Float16* Xl = Xh + (size_t)8 * S * D;           // 1.57M halfs each

    convert_kernel<<<1536,           256, 0, stream>>>(X, Xh, Xl);
    gram_kernel   <<<dim3(16, 8, 8), 256, 0, stream>>>(Xh, Xl, G);
    visxw_kernel  <<<dim3(64, 8),    256, 0, stream>>>(X, Wm, G, P, wv);
    head_kernel   <<<8,              256, 0, stream>>>(P, wv, out);
}